// Round 9
// baseline (2235.526 us; speedup 1.0000x reference)
//
#include <hip/hip_runtime.h>
#include <math.h>

typedef __bf16 bf16;
typedef float f32x4 __attribute__((ext_vector_type(4)));
typedef bf16  bf16x4 __attribute__((ext_vector_type(4)));
typedef bf16  bf16x8 __attribute__((ext_vector_type(8)));

#define N_B  64
#define N_L  256
#define N_H  16
#define N_D  2048
#define N_HD 128
#define M_TOT (N_B * N_L)   // 16384

static __device__ __forceinline__ float bfbits_lo(unsigned u) {
  union { unsigned u; float f; } c; c.u = u << 16; return c.f;
}
static __device__ __forceinline__ float bfbits_hi(unsigned u) {
  union { unsigned u; float f; } c; c.u = u & 0xffff0000u; return c.f;
}

static __device__ __forceinline__ f32x4 shflx4(f32x4 v, int m) {
  f32x4 r;
  r[0] = __shfl_xor(v[0], m);
  r[1] = __shfl_xor(v[1], m);
  r[2] = __shfl_xor(v[2], m);
  r[3] = __shfl_xor(v[3], m);
  return r;
}
static __device__ __forceinline__ f32x4 max4(f32x4 a, f32x4 b) {
  f32x4 r;
  r[0] = fmaxf(a[0], b[0]); r[1] = fmaxf(a[1], b[1]);
  r[2] = fmaxf(a[2], b[2]); r[3] = fmaxf(a[3], b[3]);
  return r;
}

// ---------------- prep kernels ----------------
__global__ void k_cast_x(const float* __restrict__ x, bf16* __restrict__ xb, int n4) {
  int i = blockIdx.x * blockDim.x + threadIdx.x;
  int st = gridDim.x * blockDim.x;
  for (; i < n4; i += st) {
    float4 v = ((const float4*)x)[i];
    bf16x4 o;
    o[0] = (bf16)v.x; o[1] = (bf16)v.y; o[2] = (bf16)v.z; o[3] = (bf16)v.w;
    ((bf16x4*)xb)[i] = o;
  }
}

__global__ void k_transpose_w(const float* __restrict__ w, bf16* __restrict__ wt) {
  __shared__ float t[32][33];
  int n0 = blockIdx.x * 32, k0 = blockIdx.y * 32;
  t[threadIdx.y][threadIdx.x] = w[(size_t)(k0 + threadIdx.y) * N_D + n0 + threadIdx.x];
  __syncthreads();
  wt[(size_t)(n0 + threadIdx.y) * N_D + k0 + threadIdx.x] = (bf16)t[threadIdx.x][threadIdx.y];
}

__global__ void k_trig(float2* __restrict__ tab) {
  int idx = blockIdx.x * blockDim.x + threadIdx.x;
  if (idx < N_L * (N_HD / 2)) {
    int l = idx >> 6, i = idx & 63;
    float ang = (float)l * powf(10000.0f, -(float)(2 * i) / 128.0f);
    tab[idx].x = cosf(ang);
    tab[idx].y = sinf(ang);
  }
}

// ---------------- 256x256 MFMA GEMM, 4 waves x 128x128 ----------------
// C[m][n] = sum_k A[m][k] * BT[n][k] + bias[n]
// LDS read traffic = sum_w (M_w+N_w)*BK*2B: 4 waves of 128x128 -> 160KB/tile/CU
// (incl. writes) < MFMA floor (~2484 cy/tile) -> MFMA-bound phases.
// Phases: P0 (kk0,nh0), P1 (kk0,nh1), P2 (kk1,nh0), P3 (kk1,nh1); reads issued
// one phase ahead (counted lgkm). Stage A@P0 / B@P1 one tile ahead.
// vm ledger (FIXED r8 race): B staged in chunk order {0,1,4,5,2,3,6,7} so
// vm(4)@P2 retires 8xA + B rows {0-63,128-191} = exactly what P3 reads;
// remaining B rows {64-127,192-255} retire at vm(0)@P3 before next P0 reads.
// MODE 1: fp32 row-major. MODE 2: bf16 [b][h][d][l] (V^T). MODE 3: bf16 + RoPE.

#define GLOAD(GP, LP) __builtin_amdgcn_global_load_lds( \
    (const __attribute__((address_space(1))) void*)(GP), \
    (__attribute__((address_space(3))) void*)(LP), 16, 0, 0)
#define BARR()  __builtin_amdgcn_s_barrier()
#define SCHED() __builtin_amdgcn_sched_barrier(0)
#define PRIO1() __builtin_amdgcn_s_setprio(1)
#define PRIO0() __builtin_amdgcn_s_setprio(0)
#define WAITLGKM4()  asm volatile("s_waitcnt lgkmcnt(4)" ::: "memory")
#define WAITLGKM12() asm volatile("s_waitcnt lgkmcnt(12)" ::: "memory")
#define WAITVM4()    asm volatile("s_waitcnt vmcnt(4)" ::: "memory")
#define WAITVM0()    asm volatile("s_waitcnt vmcnt(0)" ::: "memory")

// Stage a full 256-row x 64-col panel (8 chunks of 32 rows); KT masked &31 so
// tail tiles stage in-range (never-read) data.
#define STAGE_A(KT, BUFA) do { \
  _Pragma("unroll") for (int c_ = 0; c_ < 8; ++c_) \
    GLOAD(Ag + (size_t)srcA[c_] + (size_t)((KT) & 31) * 64, (BUFA) + ldsOff[c_]); \
} while (0)
// B issue order matters for the vm(4)@P2 ledger: oldest-4 B = rows read at P3.
#define STAGE_B(KT, BUFB) do { \
  const int bo_[8] = {0, 1, 4, 5, 2, 3, 6, 7}; \
  _Pragma("unroll") for (int q_ = 0; q_ < 8; ++q_) { \
    const int c_ = bo_[q_]; \
    GLOAD(Bg + (size_t)srcB[c_] + (size_t)((KT) & 31) * 64, (BUFB) + ldsOff[c_]); \
  } \
} while (0)

// A bank: 8 m-frags at k-slice KK (8 x ds_read_b128)
#define RD_A(DST, KK, BUFA) do { \
  _Pragma("unroll") for (int i_ = 0; i_ < 8; ++i_) { \
    const int R_ = wm * 128 + i_ * 16 + lr; \
    DST[i_] = *(const bf16x8*)&(BUFA)[R_ * 64 + ((((KK) * 4 + lg) ^ (R_ & 7)) << 3)]; \
  } \
} while (0)
// B bank: 4 n-frags of n-half NH at k-slice KK
#define RD_B(DST, NH, KK, BUFB) do { \
  _Pragma("unroll") for (int j_ = 0; j_ < 4; ++j_) { \
    const int R_ = wn * 128 + (NH) * 64 + j_ * 16 + lr; \
    DST[j_] = *(const bf16x8*)&(BUFB)[R_ * 64 + ((((KK) * 4 + lg) ^ (R_ & 7)) << 3)]; \
  } \
} while (0)

// 32 independent MFMAs: 8 m-frags x 4 n-frags of half NH
#define MFMA32(AB, BB, NH) do { \
  _Pragma("unroll") for (int i_ = 0; i_ < 8; ++i_) \
  _Pragma("unroll") for (int j_ = 0; j_ < 4; ++j_) \
    acc[i_][(NH) * 4 + j_] = __builtin_amdgcn_mfma_f32_16x16x32_bf16( \
        AB[i_], BB[j_], acc[i_][(NH) * 4 + j_], 0, 0, 0); \
} while (0)

// lgkm ledger (per wave): P0 issues 4 (16 out) lgkm4 drains prev-P3's 12;
// P1 issues 12 (16) lgkm12 drains P0's 4; P2 issues 4 (16) lgkm4 drains P1's 12;
// P3 issues 12 (16) lgkm12 drains P2's 4.
#define TILE(T, CA, CB, OA, OB) do { \
  /* P0: (kk0,nh0) */ \
  STAGE_A((T) + 1, OA); \
  RD_B(B1b, 1, 0, CB); \
  SCHED(); WAITLGKM4(); SCHED(); \
  PRIO1(); MFMA32(A0b, B0b, 0); PRIO0(); \
  SCHED(); BARR(); SCHED(); \
  /* P1: (kk0,nh1) */ \
  STAGE_B((T) + 1, OB); \
  RD_A(A1b, 1, CA); RD_B(B0b, 0, 1, CB); \
  SCHED(); WAITLGKM12(); SCHED(); \
  PRIO1(); MFMA32(A0b, B1b, 1); PRIO0(); \
  SCHED(); BARR(); SCHED(); \
  /* P2: (kk1,nh0) */ \
  RD_B(B1b, 1, 1, CB); \
  SCHED(); WAITLGKM4(); SCHED(); \
  PRIO1(); MFMA32(A1b, B0b, 0); PRIO0(); \
  SCHED(); WAITVM4(); BARR(); SCHED(); \
  /* P3: (kk1,nh1) */ \
  RD_A(A0b, 0, OA); RD_B(B0b, 0, 0, OB); \
  SCHED(); WAITLGKM12(); SCHED(); \
  PRIO1(); MFMA32(A1b, B1b, 1); PRIO0(); \
  SCHED(); WAITVM0(); BARR(); SCHED(); \
} while (0)

template<int MODE>
__global__ __launch_bounds__(256, 1) void k_gemm256(
    const bf16* __restrict__ A, const bf16* __restrict__ BT,
    const float* __restrict__ bias, void* __restrict__ dstv,
    const float2* __restrict__ tab)
{
  __shared__ bf16 lds[2][2][256 * 64];   // [parity][A=0/B=1], 128 KB
  const int bid = blockIdx.x;
  // XCD-aware: XCD (bid&7) owns an 8-tile m-strip, sweeps bn fast.
  const int xcd = bid & 7, idx = bid >> 3;
  const int bm = xcd * 8 + (idx >> 3), bn = idx & 7;
  const int m0 = bm * 256, n0 = bn * 256;
  const int tid = threadIdx.x;
  const int wave = tid >> 6, lane = tid & 63;
  const int wm = wave >> 1, wn = wave & 1;
  const int lr = lane & 15, lg = lane >> 4;
  const bf16* __restrict__ Ag = A;
  const bf16* __restrict__ Bg = BT;

  // staging addresses: thread covers granule (tid&7) of row (c*32 + tid>>3)
  int srcA[8], srcB[8], ldsOff[8];
  {
    const int g7 = tid & 7, rr = tid >> 3;
    const int swz = (g7 ^ (rr & 7)) << 3;
#pragma unroll
    for (int c = 0; c < 8; ++c) {
      srcA[c] = (m0 + c * 32 + rr) * N_D + swz;
      srcB[c] = (n0 + c * 32 + rr) * N_D + swz;
      ldsOff[c] = (c * 32 + wave * 8) * 64;
    }
  }

  bf16* bufA0 = &lds[0][0][0];
  bf16* bufB0 = &lds[0][1][0];
  bf16* bufA1 = &lds[1][0][0];
  bf16* bufB1 = &lds[1][1][0];

  f32x4 acc[8][8];
#pragma unroll
  for (int i = 0; i < 8; ++i)
#pragma unroll
    for (int j = 0; j < 8; ++j)
      acc[i][j] = (f32x4){0.f, 0.f, 0.f, 0.f};

  bf16x8 A0b[8], A1b[8], B0b[4], B1b[4];

  // prologue: stage tile0 fully, drain, preload (kk0, nh0) operands
  STAGE_A(0, bufA0); STAGE_B(0, bufB0);
  SCHED(); WAITVM0(); BARR(); SCHED();
  RD_A(A0b, 0, bufA0); RD_B(B0b, 0, 0, bufB0);
  SCHED();

#pragma unroll 1
  for (int t = 0; t < N_D / 64; t += 2) {
    TILE(t,     bufA0, bufB0, bufA1, bufB1);
    TILE(t + 1, bufA1, bufB1, bufA0, bufB0);
  }

  // ---- epilogue ----
#pragma unroll
  for (int i = 0; i < 8; ++i) {
#pragma unroll
    for (int r = 0; r < 4; ++r) {
      const int m = m0 + wm * 128 + i * 16 + lg * 4 + r;
#pragma unroll
      for (int j = 0; j < 8; ++j) {
        const int n = n0 + wn * 128 + j * 16 + lr;
        float v = acc[i][j][r] + bias[n];
        if (MODE == 3) {
          // fused RoPE: lanes lr, lr^1 hold adjacent d at the same row m
          float partner = __shfl_xor(v, 1);
          const int d = n & 127, l = m & 255;
          float2 cs = tab[(l << 6) | (d >> 1)];
          v = (d & 1) ? (v * cs.x + partner * cs.y) : (v * cs.x - partner * cs.y);
        }
        if (MODE == 0 || MODE == 3) {
          bf16* dst = (bf16*)dstv;
          const int b = m >> 8, l = m & 255;
          const int h = n >> 7, d = n & 127;
          dst[(((size_t)b * N_H + h) * N_L + l) * N_HD + d] = (bf16)v;
        } else if (MODE == 2) {
          bf16* dst = (bf16*)dstv;
          const int b = m >> 8, l = m & 255;
          const int h = n >> 7, d = n & 127;
          dst[(((size_t)b * N_H + h) * N_HD + d) * N_L + l] = (bf16)v;
        } else {
          float* dst = (float*)dstv;
          dst[(size_t)m * N_D + n] = v;
        }
      }
    }
  }
}

// ---------------- MFMA flash attention: one block per (b,h), 8 waves ----------------
// Q,K in [b][h][l][d] (RoPE applied). Vt in [b][h][d][l]. O to [b][l][h][d].
__global__ __launch_bounds__(512) void k_attn_mfma(
    const bf16* __restrict__ Q, const bf16* __restrict__ K,
    const bf16* __restrict__ Vt, bf16* __restrict__ O)
{
  __shared__ bf16 Kl[N_L * N_HD];   // 64KB; row j = 256B = 16 granules; granule g holds src granule g^(j&7)
  __shared__ bf16 Pl[8][16][56];    // per-wave P staging; 112B row stride

  const int bh = blockIdx.x;
  const int b = bh >> 4, h = bh & 15;
  const int tid = threadIdx.x;
  const int wave = tid >> 6, lane = tid & 63;
  const int c = lane & 15, g8 = lane >> 4;

  const bf16* Qg = Q + (size_t)bh * (N_L * N_HD);
  const bf16* Kg = K + (size_t)bh * (N_L * N_HD);
  const bf16* Vg = Vt + (size_t)bh * (N_L * N_HD);

#pragma unroll
  for (int t = 0; t < 8; ++t) {
    int idx = tid + 512 * t;            // 16B-granule index, 4096 total
    int row = idx >> 4, g = idx & 15;
    const bf16* src = Kg + row * N_HD + ((g ^ (row & 7)) << 3);
    __builtin_amdgcn_global_load_lds(
        (const __attribute__((address_space(1))) void*)src,
        (__attribute__((address_space(3))) void*)(Kl + (size_t)wave * 512 + (size_t)t * 4096),
        16, 0, 0);
  }
  __syncthreads();

  const float scale = 0.08838834764831843f;  // 1/sqrt(128)

  for (int half = 0; half < 2; ++half) {
    const int qb = half ? (15 - wave) : wave;
    const int q0 = qb * 16;

    bf16x8 qf[4];
#pragma unroll
    for (int dk = 0; dk < 4; ++dk)
      qf[dk] = *(const bf16x8*)(Qg + (size_t)(q0 + c) * N_HD + dk * 32 + g8 * 8);

    f32x4 o[8];
#pragma unroll
    for (int dj = 0; dj < 8; ++dj) o[dj] = (f32x4){0.f, 0.f, 0.f, 0.f};
    f32x4 mrow = (f32x4){-INFINITY, -INFINITY, -INFINITY, -INFINITY};
    f32x4 lrow = (f32x4){0.f, 0.f, 0.f, 0.f};

    const int nsteps = ((q0 + 15) >> 5) + 1;
    for (int js = 0; js < nsteps; ++js) {
      const int j0 = js * 32;

      bf16x8 vf[4];
#pragma unroll
      for (int dj = 0; dj < 4; ++dj)
        vf[dj] = *(const bf16x8*)(Vg + (size_t)(dj * 16 + c) * N_L + j0 + g8 * 8);

      f32x4 s0 = (f32x4){0.f, 0.f, 0.f, 0.f};
      f32x4 s1 = (f32x4){0.f, 0.f, 0.f, 0.f};
#pragma unroll
      for (int dk = 0; dk < 4; ++dk) {
        int row0 = j0 + c;
        int row1 = j0 + 16 + c;
        bf16x8 kf0 = *(const bf16x8*)(Kl + row0 * N_HD + (((dk * 4 + g8) ^ (row0 & 7)) << 3));
        bf16x8 kf1 = *(const bf16x8*)(Kl + row1 * N_HD + (((dk * 4 + g8) ^ (row1 & 7)) << 3));
        s0 = __builtin_amdgcn_mfma_f32_16x16x32_bf16(qf[dk], kf0, s0, 0, 0, 0);
        s1 = __builtin_amdgcn_mfma_f32_16x16x32_bf16(qf[dk], kf1, s1, 0, 0, 0);
      }

      // mask whenever the tile touches the upper triangle: j0+31 > q0
      f32x4 sv0, sv1;
#pragma unroll
      for (int r = 0; r < 4; ++r) { sv0[r] = s0[r] * scale; sv1[r] = s1[r] * scale; }
      if (j0 + 31 > q0) {
#pragma unroll
        for (int r = 0; r < 4; ++r) {
          int q = q0 + g8 * 4 + r;
          if (j0 + c > q)      sv0[r] = -INFINITY;
          if (j0 + 16 + c > q) sv1[r] = -INFINITY;
        }
      }

      f32x4 mx = max4(sv0, sv1);
      mx = max4(mx, shflx4(mx, 1));
      mx = max4(mx, shflx4(mx, 2));
      mx = max4(mx, shflx4(mx, 4));
      mx = max4(mx, shflx4(mx, 8));
      f32x4 mnew = max4(mrow, mx);
      f32x4 resc, p0, p1;
#pragma unroll
      for (int r = 0; r < 4; ++r) {
        resc[r] = __expf(mrow[r] - mnew[r]);
        p0[r] = __expf(sv0[r] - mnew[r]);
        p1[r] = __expf(sv1[r] - mnew[r]);
      }
      f32x4 rsum = p0 + p1;
      rsum += shflx4(rsum, 1);
      rsum += shflx4(rsum, 2);
      rsum += shflx4(rsum, 4);
      rsum += shflx4(rsum, 8);
      lrow = lrow * resc + rsum;
      mrow = mnew;
#pragma unroll
      for (int dj = 0; dj < 8; ++dj) o[dj] *= resc;

#pragma unroll
      for (int r = 0; r < 4; ++r) {
        Pl[wave][g8 * 4 + r][c] = (bf16)p0[r];
        Pl[wave][g8 * 4 + r][16 + c] = (bf16)p1[r];
      }
      bf16x8 pf = *(const bf16x8*)&Pl[wave][c][g8 * 8];

      bf16x8 vg[4];
#pragma unroll
      for (int dj = 0; dj < 4; ++dj)
        vg[dj] = *(const bf16x8*)(Vg + (size_t)((dj + 4) * 16 + c) * N_L + j0 + g8 * 8);

#pragma unroll
      for (int dj = 0; dj < 4; ++dj)
        o[dj] = __builtin_amdgcn_mfma_f32_16x16x32_bf16(pf, vf[dj], o[dj], 0, 0, 0);
#pragma unroll
      for (int dj = 0; dj < 4; ++dj)
        o[dj + 4] = __builtin_amdgcn_mfma_f32_16x16x32_bf16(pf, vg[dj], o[dj + 4], 0, 0, 0);
    }

    f32x4 inv;
#pragma unroll
    for (int r = 0; r < 4; ++r) inv[r] = 1.0f / lrow[r];
#pragma unroll
    for (int dj = 0; dj < 8; ++dj) {
      f32x4 ov = o[dj] * inv;
#pragma unroll
      for (int r = 0; r < 4; ++r) {
        int q = q0 + g8 * 4 + r;
        int d = dj * 16 + c;
        O[(((size_t)b * N_L + q) * N_H + h) * N_HD + d] = (bf16)ov[r];
      }
    }
  }
}

// ---------------- launch ----------------
extern "C" void kernel_launch(void* const* d_in, const int* in_sizes, int n_in,
                              void* d_out, int out_size, void* d_ws, size_t ws_size,
                              hipStream_t stream) {
  const float* x  = (const float*)d_in[0];
  const float* wq = (const float*)d_in[1];
  const float* bq = (const float*)d_in[2];
  const float* wk = (const float*)d_in[3];
  const float* bk = (const float*)d_in[4];
  const float* wv = (const float*)d_in[5];
  const float* bv = (const float*)d_in[6];
  const float* wo = (const float*)d_in[7];
  const float* bo = (const float*)d_in[8];

  char* ws = (char*)d_ws;
  const size_t WSZ = (size_t)N_D * N_D * sizeof(bf16);    // 8 MB per transposed weight
  const size_t XSZ = (size_t)M_TOT * N_D * sizeof(bf16);  // 64 MB per activation tensor
  bf16* wqT = (bf16*)(ws);
  bf16* wkT = (bf16*)(ws + WSZ);
  bf16* wvT = (bf16*)(ws + 2 * WSZ);
  bf16* woT = (bf16*)(ws + 3 * WSZ);
  bf16* xb  = (bf16*)(ws + 4 * WSZ);
  bf16* Qb  = (bf16*)(ws + 4 * WSZ + XSZ);
  bf16* Kb  = (bf16*)(ws + 4 * WSZ + 2 * XSZ);
  bf16* Vb  = (bf16*)(ws + 4 * WSZ + 3 * XSZ);  // holds V^T: [b][h][d][l]
  bf16* Ob  = (bf16*)(ws + 4 * WSZ + 4 * XSZ);
  float2* tab = (float2*)(ws + 4 * WSZ + 5 * XSZ);

  k_cast_x<<<2048, 256, 0, stream>>>(x, xb, M_TOT * N_D / 4);
  dim3 tb(32, 32), tg(64, 64);
  k_transpose_w<<<tg, tb, 0, stream>>>(wq, wqT);
  k_transpose_w<<<tg, tb, 0, stream>>>(wk, wkT);
  k_transpose_w<<<tg, tb, 0, stream>>>(wv, wvT);
  k_transpose_w<<<tg, tb, 0, stream>>>(wo, woT);
  k_trig<<<64, 256, 0, stream>>>(tab);

  const int grid = (M_TOT / 256) * (N_D / 256);  // 512
  k_gemm256<3><<<grid, 256, 0, stream>>>(xb, wqT, bq, Qb, tab);   // Q proj + RoPE
  k_gemm256<3><<<grid, 256, 0, stream>>>(xb, wkT, bk, Kb, tab);   // K proj + RoPE
  k_gemm256<2><<<grid, 256, 0, stream>>>(xb, wvT, bv, Vb, tab);   // V proj, transposed

  k_attn_mfma<<<1024, 512, 0, stream>>>(Qb, Kb, Vb, Ob);
  k_gemm256<1><<<grid, 256, 0, stream>>>(Ob, woT, bo, d_out, tab);
}

// Round 10
// 999.856 us; speedup vs baseline: 2.2358x; 2.2358x over previous
//
#include <hip/hip_runtime.h>
#include <math.h>

typedef __bf16 bf16;
typedef float f32x4 __attribute__((ext_vector_type(4)));
typedef bf16  bf16x4 __attribute__((ext_vector_type(4)));
typedef bf16  bf16x8 __attribute__((ext_vector_type(8)));

#define N_B  64
#define N_L  256
#define N_H  16
#define N_D  2048
#define N_HD 128
#define M_TOT (N_B * N_L)   // 16384

static __device__ __forceinline__ f32x4 shflx4(f32x4 v, int m) {
  f32x4 r;
  r[0] = __shfl_xor(v[0], m);
  r[1] = __shfl_xor(v[1], m);
  r[2] = __shfl_xor(v[2], m);
  r[3] = __shfl_xor(v[3], m);
  return r;
}
static __device__ __forceinline__ f32x4 max4(f32x4 a, f32x4 b) {
  f32x4 r;
  r[0] = fmaxf(a[0], b[0]); r[1] = fmaxf(a[1], b[1]);
  r[2] = fmaxf(a[2], b[2]); r[3] = fmaxf(a[3], b[3]);
  return r;
}

// ---------------- prep kernels ----------------
__global__ void k_cast_x(const float* __restrict__ x, bf16* __restrict__ xb, int n4) {
  int i = blockIdx.x * blockDim.x + threadIdx.x;
  int st = gridDim.x * blockDim.x;
  for (; i < n4; i += st) {
    float4 v = ((const float4*)x)[i];
    bf16x4 o;
    o[0] = (bf16)v.x; o[1] = (bf16)v.y; o[2] = (bf16)v.z; o[3] = (bf16)v.w;
    ((bf16x4*)xb)[i] = o;
  }
}

__global__ void k_transpose_w(const float* __restrict__ w, bf16* __restrict__ wt) {
  __shared__ float t[32][33];
  int n0 = blockIdx.x * 32, k0 = blockIdx.y * 32;
  t[threadIdx.y][threadIdx.x] = w[(size_t)(k0 + threadIdx.y) * N_D + n0 + threadIdx.x];
  __syncthreads();
  wt[(size_t)(n0 + threadIdx.y) * N_D + k0 + threadIdx.x] = (bf16)t[threadIdx.x][threadIdx.y];
}

__global__ void k_trig(float2* __restrict__ tab) {
  int idx = blockIdx.x * blockDim.x + threadIdx.x;
  if (idx < N_L * (N_HD / 2)) {
    int l = idx >> 6, i = idx & 63;
    float ang = (float)l * powf(10000.0f, -(float)(2 * i) / 128.0f);
    tab[idx].x = cosf(ang);
    tab[idx].y = sinf(ang);
  }
}

// ---------------- 256x256 MFMA GEMM: A via LDS, B direct from L2 ----------------
// C[m][n] = sum_k A[m][k] * BT[n][k] + bias[n]
// 8 waves (2m x 4n), per-wave 128x64 (acc[8][4], ~252 regs: r7-verified budget).
// r7 diagnosis: CU-level LDS read pipe (8 waves x 12 b128/phase ~ 4600 cy/K-tile)
// was the binding resource. Fix: B-frags read straight from global (panel is
// L2-resident; wave-private, no barriers), halving LDS reads + halving staging.
// Per-phase balance/CU: MFMA 1242 cy > LDS A 1050 cy > L2-B ~500 cy -> MFMA-bound.
// A dbuf ledger: stage@P0 -> vmcnt(4)+BARRIER@P1 -> read@P1 -> consume@P0(t+1).
// MODE 1: fp32 row-major. MODE 2: bf16 [b][h][d][l] (V^T). MODE 3: bf16 + RoPE.

#define GLOAD(GP, LP) __builtin_amdgcn_global_load_lds( \
    (const __attribute__((address_space(1))) void*)(GP), \
    (__attribute__((address_space(3))) void*)(LP), 16, 0, 0)
#define BARR()  __builtin_amdgcn_s_barrier()
#define SCHED() __builtin_amdgcn_sched_barrier(0)
#define PRIO1() __builtin_amdgcn_s_setprio(1)
#define PRIO0() __builtin_amdgcn_s_setprio(0)
#define WAITLGKM8() asm volatile("s_waitcnt lgkmcnt(8)" ::: "memory")
#define WAITVM4()   asm volatile("s_waitcnt vmcnt(4)" ::: "memory")
#define WAITVM0()   asm volatile("s_waitcnt vmcnt(0)" ::: "memory")

// Stage full 256x64 A-tile (4 chunks of 64 rows); KT masked &31 -> tail stages
// in-range never-read data.
#define STAGE_A(KT, BUF) do { \
  _Pragma("unroll") for (int c_ = 0; c_ < 4; ++c_) \
    GLOAD(Ag + (size_t)srcA[c_] + (size_t)((KT) & 31) * 64, (BUF) + ldsOffA[c_]); \
} while (0)

// A bank: 8 m-frags at k-slice KK (8 x ds_read_b128, XOR-granule swizzled)
#define RD_A(DST, KK, BUF) do { \
  _Pragma("unroll") for (int i_ = 0; i_ < 8; ++i_) { \
    const int R_ = wm * 128 + i_ * 16 + lr; \
    DST[i_] = *(const bf16x8*)&(BUF)[R_ * 64 + ((((KK) * 4 + lg) ^ (R_ & 7)) << 3)]; \
  } \
} while (0)

// B bank: 4 n-frags direct from global (L2-hit); compiler tracks the vmcnt.
#define LD_B(DST, KT, KK) do { \
  _Pragma("unroll") for (int j_ = 0; j_ < 4; ++j_) \
    DST[j_] = *(const bf16x8*)(Brow[j_] + (size_t)((KT) & 31) * 64 + (KK) * 32); \
} while (0)

// 32 independent MFMAs: 8 m-frags x 4 n-frags
#define MFMA32(AB, BB) do { \
  _Pragma("unroll") for (int i_ = 0; i_ < 8; ++i_) \
  _Pragma("unroll") for (int j_ = 0; j_ < 4; ++j_) \
    acc[i_][j_] = __builtin_amdgcn_mfma_f32_16x16x32_bf16( \
        AB[i_], BB[j_], acc[i_][j_], 0, 0, 0); \
} while (0)

template<int MODE>
__global__ __launch_bounds__(512, 1) void k_gemm256(
    const bf16* __restrict__ A, const bf16* __restrict__ BT,
    const float* __restrict__ bias, void* __restrict__ dstv,
    const float2* __restrict__ tab)
{
  __shared__ bf16 As[2][256 * 64];   // 64 KB double-buffered A
  const int bid = blockIdx.x;
  // XCD-aware: concurrent blocks on one XCD share bn (B panel working set
  // = 4 x 1MB panels, fits 4MB L2); bm sweeps fast within the XCD m-strip.
  const int xcd = bid & 7, idx = bid >> 3;
  const int bm = xcd * 8 + (idx & 7), bn = idx >> 3;
  const int m0 = bm * 256, n0 = bn * 256;
  const int tid = threadIdx.x;
  const int wave = tid >> 6, lane = tid & 63;
  const int wm = wave >> 2, wn = wave & 3;
  const int lr = lane & 15, lg = lane >> 4;
  const bf16* __restrict__ Ag = A;
  const bf16* __restrict__ Bg = BT;

  // A staging addresses: lane covers granule (tid&7) of row (c*64 + tid>>3)
  int srcA[4], ldsOffA[4];
  {
    const int g7 = tid & 7, rr = tid >> 3;
    const int swz = (g7 ^ (rr & 7)) << 3;
#pragma unroll
    for (int c = 0; c < 4; ++c) {
      srcA[c] = (m0 + c * 64 + rr) * N_D + swz;
      ldsOffA[c] = (c * 64 + wave * 8) * 64;
    }
  }
  // B fragment row pointers (wave-private)
  const bf16* Brow[4];
#pragma unroll
  for (int j = 0; j < 4; ++j)
    Brow[j] = Bg + (size_t)(n0 + wn * 64 + j * 16 + lr) * N_D + lg * 8;

  f32x4 acc[8][4];
#pragma unroll
  for (int i = 0; i < 8; ++i)
#pragma unroll
    for (int j = 0; j < 4; ++j)
      acc[i][j] = (f32x4){0.f, 0.f, 0.f, 0.f};

  bf16x8 A0b[8], A1b[8], B0b[4], B1b[4];

  // prologue: stage A tile0, drain, preload kk0 operands
  STAGE_A(0, As[0]);
  SCHED(); WAITVM0(); BARR(); SCHED();
  RD_A(A0b, 0, As[0]);
  LD_B(B0b, 0, 0);
  SCHED();

#pragma unroll 1
  for (int t = 0; t < N_D / 64; ++t) {
    const int buf = t & 1;
    // ---- P0: compute (kk0); prefetch kk1 operands; stage A(t+1) ----
    STAGE_A(t + 1, As[buf ^ 1]);
    LD_B(B1b, t, 1);
    RD_A(A1b, 1, As[buf]);
    SCHED(); WAITLGKM8(); SCHED();      // drain prev-phase A reads (bank0)
    PRIO1(); MFMA32(A0b, B0b); PRIO0(); // compiler inserts vmcnt for B0b
    SCHED(); BARR(); SCHED();
    // ---- P1: compute (kk1); prefetch next tile kk0 operands ----
    WAITVM4();                          // retire this tile's 4 stage loads
    BARR(); SCHED();                    // all waves' stages visible in LDS
    LD_B(B0b, t + 1, 0);
    RD_A(A0b, 0, As[buf ^ 1]);
    SCHED(); WAITLGKM8(); SCHED();      // drain P0's A reads (bank1)
    PRIO1(); MFMA32(A1b, B1b); PRIO0(); // compiler inserts vmcnt for B1b
    SCHED(); BARR(); SCHED();
  }

  // ---- epilogue ----
#pragma unroll
  for (int i = 0; i < 8; ++i) {
#pragma unroll
    for (int r = 0; r < 4; ++r) {
      const int m = m0 + wm * 128 + i * 16 + lg * 4 + r;
#pragma unroll
      for (int j = 0; j < 4; ++j) {
        const int n = n0 + wn * 64 + j * 16 + lr;
        float v = acc[i][j][r] + bias[n];
        if (MODE == 3) {
          // fused RoPE: lanes lr, lr^1 hold adjacent d at the same row m
          float partner = __shfl_xor(v, 1);
          const int d = n & 127, l = m & 255;
          float2 cs = tab[(l << 6) | (d >> 1)];
          v = (d & 1) ? (v * cs.x + partner * cs.y) : (v * cs.x - partner * cs.y);
        }
        if (MODE == 0 || MODE == 3) {
          bf16* dst = (bf16*)dstv;
          const int b = m >> 8, l = m & 255;
          const int h = n >> 7, d = n & 127;
          dst[(((size_t)b * N_H + h) * N_L + l) * N_HD + d] = (bf16)v;
        } else if (MODE == 2) {
          bf16* dst = (bf16*)dstv;
          const int b = m >> 8, l = m & 255;
          const int h = n >> 7, d = n & 127;
          dst[(((size_t)b * N_H + h) * N_HD + d) * N_L + l] = (bf16)v;
        } else {
          float* dst = (float*)dstv;
          dst[(size_t)m * N_D + n] = v;
        }
      }
    }
  }
}

// ---------------- MFMA flash attention: one block per (b,h), 8 waves ----------------
// Q,K in [b][h][l][d] (RoPE applied). Vt in [b][h][d][l]. O to [b][l][h][d].
__global__ __launch_bounds__(512) void k_attn_mfma(
    const bf16* __restrict__ Q, const bf16* __restrict__ K,
    const bf16* __restrict__ Vt, bf16* __restrict__ O)
{
  __shared__ bf16 Kl[N_L * N_HD];   // 64KB; row j = 256B = 16 granules; granule g holds src granule g^(j&7)
  __shared__ bf16 Pl[8][16][56];    // per-wave P staging; 112B row stride

  const int bh = blockIdx.x;
  const int b = bh >> 4, h = bh & 15;
  const int tid = threadIdx.x;
  const int wave = tid >> 6, lane = tid & 63;
  const int c = lane & 15, g8 = lane >> 4;

  const bf16* Qg = Q + (size_t)bh * (N_L * N_HD);
  const bf16* Kg = K + (size_t)bh * (N_L * N_HD);
  const bf16* Vg = Vt + (size_t)bh * (N_L * N_HD);

#pragma unroll
  for (int t = 0; t < 8; ++t) {
    int idx = tid + 512 * t;            // 16B-granule index, 4096 total
    int row = idx >> 4, g = idx & 15;
    const bf16* src = Kg + row * N_HD + ((g ^ (row & 7)) << 3);
    __builtin_amdgcn_global_load_lds(
        (const __attribute__((address_space(1))) void*)src,
        (__attribute__((address_space(3))) void*)(Kl + (size_t)wave * 512 + (size_t)t * 4096),
        16, 0, 0);
  }
  __syncthreads();

  const float scale = 0.08838834764831843f;  // 1/sqrt(128)

  for (int half = 0; half < 2; ++half) {
    const int qb = half ? (15 - wave) : wave;
    const int q0 = qb * 16;

    bf16x8 qf[4];
#pragma unroll
    for (int dk = 0; dk < 4; ++dk)
      qf[dk] = *(const bf16x8*)(Qg + (size_t)(q0 + c) * N_HD + dk * 32 + g8 * 8);

    f32x4 o[8];
#pragma unroll
    for (int dj = 0; dj < 8; ++dj) o[dj] = (f32x4){0.f, 0.f, 0.f, 0.f};
    f32x4 mrow = (f32x4){-INFINITY, -INFINITY, -INFINITY, -INFINITY};
    f32x4 lrow = (f32x4){0.f, 0.f, 0.f, 0.f};

    const int nsteps = ((q0 + 15) >> 5) + 1;
    for (int js = 0; js < nsteps; ++js) {
      const int j0 = js * 32;

      bf16x8 vf[4];
#pragma unroll
      for (int dj = 0; dj < 4; ++dj)
        vf[dj] = *(const bf16x8*)(Vg + (size_t)(dj * 16 + c) * N_L + j0 + g8 * 8);

      f32x4 s0 = (f32x4){0.f, 0.f, 0.f, 0.f};
      f32x4 s1 = (f32x4){0.f, 0.f, 0.f, 0.f};
#pragma unroll
      for (int dk = 0; dk < 4; ++dk) {
        int row0 = j0 + c;
        int row1 = j0 + 16 + c;
        bf16x8 kf0 = *(const bf16x8*)(Kl + row0 * N_HD + (((dk * 4 + g8) ^ (row0 & 7)) << 3));
        bf16x8 kf1 = *(const bf16x8*)(Kl + row1 * N_HD + (((dk * 4 + g8) ^ (row1 & 7)) << 3));
        s0 = __builtin_amdgcn_mfma_f32_16x16x32_bf16(qf[dk], kf0, s0, 0, 0, 0);
        s1 = __builtin_amdgcn_mfma_f32_16x16x32_bf16(qf[dk], kf1, s1, 0, 0, 0);
      }

      // mask whenever the tile touches the upper triangle: j0+31 > q0
      f32x4 sv0, sv1;
#pragma unroll
      for (int r = 0; r < 4; ++r) { sv0[r] = s0[r] * scale; sv1[r] = s1[r] * scale; }
      if (j0 + 31 > q0) {
#pragma unroll
        for (int r = 0; r < 4; ++r) {
          int q = q0 + g8 * 4 + r;
          if (j0 + c > q)      sv0[r] = -INFINITY;
          if (j0 + 16 + c > q) sv1[r] = -INFINITY;
        }
      }

      f32x4 mx = max4(sv0, sv1);
      mx = max4(mx, shflx4(mx, 1));
      mx = max4(mx, shflx4(mx, 2));
      mx = max4(mx, shflx4(mx, 4));
      mx = max4(mx, shflx4(mx, 8));
      f32x4 mnew = max4(mrow, mx);
      f32x4 resc, p0, p1;
#pragma unroll
      for (int r = 0; r < 4; ++r) {
        resc[r] = __expf(mrow[r] - mnew[r]);
        p0[r] = __expf(sv0[r] - mnew[r]);
        p1[r] = __expf(sv1[r] - mnew[r]);
      }
      f32x4 rsum = p0 + p1;
      rsum += shflx4(rsum, 1);
      rsum += shflx4(rsum, 2);
      rsum += shflx4(rsum, 4);
      rsum += shflx4(rsum, 8);
      lrow = lrow * resc + rsum;
      mrow = mnew;
#pragma unroll
      for (int dj = 0; dj < 8; ++dj) o[dj] *= resc;

#pragma unroll
      for (int r = 0; r < 4; ++r) {
        Pl[wave][g8 * 4 + r][c] = (bf16)p0[r];
        Pl[wave][g8 * 4 + r][16 + c] = (bf16)p1[r];
      }
      bf16x8 pf = *(const bf16x8*)&Pl[wave][c][g8 * 8];

      bf16x8 vg[4];
#pragma unroll
      for (int dj = 0; dj < 4; ++dj)
        vg[dj] = *(const bf16x8*)(Vg + (size_t)((dj + 4) * 16 + c) * N_L + j0 + g8 * 8);

#pragma unroll
      for (int dj = 0; dj < 4; ++dj)
        o[dj] = __builtin_amdgcn_mfma_f32_16x16x32_bf16(pf, vf[dj], o[dj], 0, 0, 0);
#pragma unroll
      for (int dj = 0; dj < 4; ++dj)
        o[dj + 4] = __builtin_amdgcn_mfma_f32_16x16x32_bf16(pf, vg[dj], o[dj + 4], 0, 0, 0);
    }

    f32x4 inv;
#pragma unroll
    for (int r = 0; r < 4; ++r) inv[r] = 1.0f / lrow[r];
#pragma unroll
    for (int dj = 0; dj < 8; ++dj) {
      f32x4 ov = o[dj] * inv;
#pragma unroll
      for (int r = 0; r < 4; ++r) {
        int q = q0 + g8 * 4 + r;
        int d = dj * 16 + c;
        O[(((size_t)b * N_L + q) * N_H + h) * N_HD + d] = (bf16)ov[r];
      }
    }
  }
}

// ---------------- launch ----------------
extern "C" void kernel_launch(void* const* d_in, const int* in_sizes, int n_in,
                              void* d_out, int out_size, void* d_ws, size_t ws_size,
                              hipStream_t stream) {
  const float* x  = (const float*)d_in[0];
  const float* wq = (const float*)d_in[1];
  const float* bq = (const float*)d_in[2];
  const float* wk = (const float*)d_in[3];
  const float* bk = (const float*)d_in[4];
  const float* wv = (const float*)d_in[5];
  const float* bv = (const float*)d_in[6];
  const float* wo = (const float*)d_in[7];
  const float* bo = (const float*)d_in[8];

  char* ws = (char*)d_ws;
  const size_t WSZ = (size_t)N_D * N_D * sizeof(bf16);    // 8 MB per transposed weight
  const size_t XSZ = (size_t)M_TOT * N_D * sizeof(bf16);  // 64 MB per activation tensor
  bf16* wqT = (bf16*)(ws);
  bf16* wkT = (bf16*)(ws + WSZ);
  bf16* wvT = (bf16*)(ws + 2 * WSZ);
  bf16* woT = (bf16*)(ws + 3 * WSZ);
  bf16* xb  = (bf16*)(ws + 4 * WSZ);
  bf16* Qb  = (bf16*)(ws + 4 * WSZ + XSZ);
  bf16* Kb  = (bf16*)(ws + 4 * WSZ + 2 * XSZ);
  bf16* Vb  = (bf16*)(ws + 4 * WSZ + 3 * XSZ);  // holds V^T: [b][h][d][l]
  bf16* Ob  = (bf16*)(ws + 4 * WSZ + 4 * XSZ);
  float2* tab = (float2*)(ws + 4 * WSZ + 5 * XSZ);

  k_cast_x<<<2048, 256, 0, stream>>>(x, xb, M_TOT * N_D / 4);
  dim3 tb(32, 32), tg(64, 64);
  k_transpose_w<<<tg, tb, 0, stream>>>(wq, wqT);
  k_transpose_w<<<tg, tb, 0, stream>>>(wk, wkT);
  k_transpose_w<<<tg, tb, 0, stream>>>(wv, wvT);
  k_transpose_w<<<tg, tb, 0, stream>>>(wo, woT);
  k_trig<<<64, 256, 0, stream>>>(tab);

  const int grid = (M_TOT / 256) * (N_D / 256);  // 512
  k_gemm256<3><<<grid, 512, 0, stream>>>(xb, wqT, bq, Qb, tab);   // Q proj + RoPE
  k_gemm256<3><<<grid, 512, 0, stream>>>(xb, wkT, bk, Kb, tab);   // K proj + RoPE
  k_gemm256<2><<<grid, 512, 0, stream>>>(xb, wvT, bv, Vb, tab);   // V proj, transposed

  k_attn_mfma<<<1024, 512, 0, stream>>>(Qb, Kb, Vb, Ob);
  k_gemm256<1><<<grid, 512, 0, stream>>>(Ob, woT, bo, d_out, tab);
}

// Round 11
// 834.612 us; speedup vs baseline: 2.6785x; 1.1980x over previous
//
#include <hip/hip_runtime.h>
#include <math.h>

typedef __bf16 bf16;
typedef float f32x4 __attribute__((ext_vector_type(4)));
typedef bf16  bf16x4 __attribute__((ext_vector_type(4)));
typedef bf16  bf16x8 __attribute__((ext_vector_type(8)));

#define N_B  64
#define N_L  256
#define N_H  16
#define N_D  2048
#define N_HD 128
#define M_TOT (N_B * N_L)   // 16384

static __device__ __forceinline__ f32x4 shflx4(f32x4 v, int m) {
  f32x4 r;
  r[0] = __shfl_xor(v[0], m);
  r[1] = __shfl_xor(v[1], m);
  r[2] = __shfl_xor(v[2], m);
  r[3] = __shfl_xor(v[3], m);
  return r;
}
static __device__ __forceinline__ f32x4 max4(f32x4 a, f32x4 b) {
  f32x4 r;
  r[0] = fmaxf(a[0], b[0]); r[1] = fmaxf(a[1], b[1]);
  r[2] = fmaxf(a[2], b[2]); r[3] = fmaxf(a[3], b[3]);
  return r;
}

// ---------------- prep kernels ----------------
__global__ void k_cast_x(const float* __restrict__ x, bf16* __restrict__ xb, int n4) {
  int i = blockIdx.x * blockDim.x + threadIdx.x;
  int st = gridDim.x * blockDim.x;
  for (; i < n4; i += st) {
    float4 v = ((const float4*)x)[i];
    bf16x4 o;
    o[0] = (bf16)v.x; o[1] = (bf16)v.y; o[2] = (bf16)v.z; o[3] = (bf16)v.w;
    ((bf16x4*)xb)[i] = o;
  }
}

__global__ void k_transpose_w(const float* __restrict__ w, bf16* __restrict__ wt) {
  __shared__ float t[32][33];
  int n0 = blockIdx.x * 32, k0 = blockIdx.y * 32;
  t[threadIdx.y][threadIdx.x] = w[(size_t)(k0 + threadIdx.y) * N_D + n0 + threadIdx.x];
  __syncthreads();
  wt[(size_t)(n0 + threadIdx.y) * N_D + k0 + threadIdx.x] = (bf16)t[threadIdx.x][threadIdx.y];
}

__global__ void k_trig(float2* __restrict__ tab) {
  int idx = blockIdx.x * blockDim.x + threadIdx.x;
  if (idx < N_L * (N_HD / 2)) {
    int l = idx >> 6, i = idx & 63;
    float ang = (float)l * powf(10000.0f, -(float)(2 * i) / 128.0f);
    tab[idx].x = cosf(ang);
    tab[idx].y = sinf(ang);
  }
}

// ---------------- 256x128 MFMA GEMM, BK=32, 2 blocks/CU ----------------
// C[m][n] = sum_k A[m][k] * BT[n][k] + bias[n]
// r10 evidence: r7's 5025 cy/tile = LDS(2816) + MFMA(2483) with ~zero overlap
// (single 8-wave block -> barrier lockstep puts LDS and MFMA in anti-phase).
// Fix: 4-wave blocks, 48KB LDS dbuf -> 2 independent blocks/CU (VGPR-capped);
// blocks decorrelate so one block's MFMA overlaps the other's LDS/HBM stalls
// (m114 mechanism). Schedule = r7-style counted waits, 2 phases/K-tile(32).
// MODE 1: fp32 row-major. MODE 2: bf16 [b][h][d][l] (V^T). MODE 3: bf16 + RoPE.

#define GLOAD(GP, LP) __builtin_amdgcn_global_load_lds( \
    (const __attribute__((address_space(1))) void*)(GP), \
    (__attribute__((address_space(3))) void*)(LP), 16, 0, 0)
#define BARR()  __builtin_amdgcn_s_barrier()
#define SCHED() __builtin_amdgcn_sched_barrier(0)
#define PRIO1() __builtin_amdgcn_s_setprio(1)
#define PRIO0() __builtin_amdgcn_s_setprio(0)
#define WAITLGKM4() asm volatile("s_waitcnt lgkmcnt(4)" ::: "memory")
#define WAITLGKM8() asm volatile("s_waitcnt lgkmcnt(8)" ::: "memory")
#define WAITVM0()   asm volatile("s_waitcnt vmcnt(0)" ::: "memory")

// Stage 256x32 A-tile (4 gloads/thread) / 128x32 B-tile (2 gloads/thread).
// KT masked &63 -> tail stages in-range never-read data.
#define STAGE_A(KT, BUF) do { \
  _Pragma("unroll") for (int c_ = 0; c_ < 4; ++c_) \
    GLOAD(Ag + (size_t)srcA[c_] + (size_t)((KT) & 63) * 32, (BUF) + c_ * 2048 + wave * 512); \
} while (0)
#define STAGE_B(KT, BUF) do { \
  _Pragma("unroll") for (int c_ = 0; c_ < 2; ++c_) \
    GLOAD(Bg + (size_t)srcB[c_] + (size_t)((KT) & 63) * 32, (BUF) + c_ * 2048 + wave * 512); \
} while (0)

// A half (MH in {0,1}): 4 frags (rows MH*64 + i*16 + lr), K=32 per b128
#define RD_A(DST, MH, BUF) do { \
  _Pragma("unroll") for (int i_ = 0; i_ < 4; ++i_) { \
    const int R_ = wm * 128 + (MH) * 64 + i_ * 16 + lr; \
    DST[i_] = *(const bf16x8*)&(BUF)[R_ * 32 + ((lg ^ (R_ & 3)) << 3)]; \
  } \
} while (0)
// B: 4 frags (rows wn*64 + j*16 + lr)
#define RD_B(DST, BUF) do { \
  _Pragma("unroll") for (int j_ = 0; j_ < 4; ++j_) { \
    const int R_ = wn * 64 + j_ * 16 + lr; \
    DST[j_] = *(const bf16x8*)&(BUF)[R_ * 32 + ((lg ^ (R_ & 3)) << 3)]; \
  } \
} while (0)

// 16 independent MFMAs: A-half MH x 4 B-frags (one MFMA covers full BK=32)
#define MFMA16(AB, BB, MH) do { \
  _Pragma("unroll") for (int i_ = 0; i_ < 4; ++i_) \
  _Pragma("unroll") for (int j_ = 0; j_ < 4; ++j_) \
    acc[(MH) * 4 + i_][j_] = __builtin_amdgcn_mfma_f32_16x16x32_bf16( \
        AB[i_], BB[j_], acc[(MH) * 4 + i_][j_], 0, 0, 0); \
} while (0)

// lgkm ledger: P0 enters with 8 out (A0b,BNXT from prev P1), issues 4 (A1b)
// -> lgkm(4) drains the 8. P1 issues 8 (A0b,BNXT) on top of 4 -> lgkm(8)
// drains A1b (oldest). vm: stages issued at P0 (6 loads), drained vm(0)+BARR
// at P1 before any wave reads the new tile. B reg banks ping-pong by parity.
#define TILE(T, CA, CB, OA, OB, BCUR, BNXT) do { \
  /* P0 */ \
  STAGE_A((T) + 1, OA); STAGE_B((T) + 1, OB); \
  RD_A(A1b, 1, CA); \
  SCHED(); WAITLGKM4(); SCHED(); \
  PRIO1(); MFMA16(A0b, BCUR, 0); PRIO0(); \
  SCHED(); BARR(); SCHED(); \
  /* P1 */ \
  WAITVM0(); BARR(); SCHED(); \
  RD_A(A0b, 0, OA); RD_B(BNXT, OB); \
  SCHED(); WAITLGKM8(); SCHED(); \
  PRIO1(); MFMA16(A1b, BCUR, 1); PRIO0(); \
  SCHED(); BARR(); SCHED(); \
} while (0)

template<int MODE>
__global__ __launch_bounds__(256, 2) void k_gemm256(
    const bf16* __restrict__ A, const bf16* __restrict__ BT,
    const float* __restrict__ bias, void* __restrict__ dstv,
    const float2* __restrict__ tab)
{
  __shared__ bf16 As[2][256 * 32];   // 2 x 16 KB
  __shared__ bf16 Bs[2][128 * 32];   // 2 x  8 KB   (48 KB total -> 2 blocks/CU)
  const int bid = blockIdx.x;
  // XCD-aware: XCD (bid&7) owns an 8-tile m-strip; bm sweeps fast (A L2-share).
  const int xcd = bid & 7, idx = bid >> 3;
  const int bm = xcd * 8 + (idx & 7), bn = idx >> 3;
  const int m0 = bm * 256, n0 = bn * 128;
  const int tid = threadIdx.x;
  const int wave = tid >> 6, lane = tid & 63;
  const int wm = wave >> 1, wn = wave & 1;
  const int lr = lane & 15, lg = lane >> 4;
  const bf16* __restrict__ Ag = A;
  const bf16* __restrict__ Bg = BT;

  // staging sources: thread covers granule gi = c*256+tid; row=gi>>2, g=gi&3
  int srcA[4], srcB[2];
  {
#pragma unroll
    for (int c = 0; c < 4; ++c) {
      const int gi = c * 256 + tid, row = gi >> 2, g = gi & 3;
      srcA[c] = (m0 + row) * N_D + ((g ^ (row & 3)) << 3);
    }
#pragma unroll
    for (int c = 0; c < 2; ++c) {
      const int gi = c * 256 + tid, row = gi >> 2, g = gi & 3;
      srcB[c] = (n0 + row) * N_D + ((g ^ (row & 3)) << 3);
    }
  }

  f32x4 acc[8][4];
#pragma unroll
  for (int i = 0; i < 8; ++i)
#pragma unroll
    for (int j = 0; j < 4; ++j)
      acc[i][j] = (f32x4){0.f, 0.f, 0.f, 0.f};

  bf16x8 A0b[4], A1b[4], Bb0[4], Bb1[4];

  // prologue: stage tile0, drain, preload A-mh0 + B
  STAGE_A(0, As[0]); STAGE_B(0, Bs[0]);
  SCHED(); WAITVM0(); BARR(); SCHED();
  RD_A(A0b, 0, As[0]); RD_B(Bb0, Bs[0]);
  SCHED();

#pragma unroll 1
  for (int t = 0; t < N_D / 32; t += 2) {
    TILE(t,     As[0], Bs[0], As[1], Bs[1], Bb0, Bb1);
    TILE(t + 1, As[1], Bs[1], As[0], Bs[0], Bb1, Bb0);
  }

  // ---- epilogue ----
#pragma unroll
  for (int i = 0; i < 8; ++i) {
#pragma unroll
    for (int r = 0; r < 4; ++r) {
      const int m = m0 + wm * 128 + i * 16 + lg * 4 + r;
#pragma unroll
      for (int j = 0; j < 4; ++j) {
        const int n = n0 + wn * 64 + j * 16 + lr;
        float v = acc[i][j][r] + bias[n];
        if (MODE == 3) {
          // fused RoPE: lanes lr, lr^1 hold adjacent d at the same row m
          float partner = __shfl_xor(v, 1);
          const int d = n & 127, l = m & 255;
          float2 cs = tab[(l << 6) | (d >> 1)];
          v = (d & 1) ? (v * cs.x + partner * cs.y) : (v * cs.x - partner * cs.y);
        }
        if (MODE == 0 || MODE == 3) {
          bf16* dst = (bf16*)dstv;
          const int b = m >> 8, l = m & 255;
          const int h = n >> 7, d = n & 127;
          dst[(((size_t)b * N_H + h) * N_L + l) * N_HD + d] = (bf16)v;
        } else if (MODE == 2) {
          bf16* dst = (bf16*)dstv;
          const int b = m >> 8, l = m & 255;
          const int h = n >> 7, d = n & 127;
          dst[(((size_t)b * N_H + h) * N_HD + d) * N_L + l] = (bf16)v;
        } else {
          float* dst = (float*)dstv;
          dst[(size_t)m * N_D + n] = v;
        }
      }
    }
  }
}

// ---------------- MFMA flash attention: one block per (b,h), 8 waves ----------------
// Q,K in [b][h][l][d] (RoPE applied). Vt in [b][h][d][l]. O to [b][l][h][d].
__global__ __launch_bounds__(512) void k_attn_mfma(
    const bf16* __restrict__ Q, const bf16* __restrict__ K,
    const bf16* __restrict__ Vt, bf16* __restrict__ O)
{
  __shared__ bf16 Kl[N_L * N_HD];   // 64KB; row j = 256B = 16 granules; granule g holds src granule g^(j&7)
  __shared__ bf16 Pl[8][16][56];    // per-wave P staging; 112B row stride

  const int bh = blockIdx.x;
  const int b = bh >> 4, h = bh & 15;
  const int tid = threadIdx.x;
  const int wave = tid >> 6, lane = tid & 63;
  const int c = lane & 15, g8 = lane >> 4;

  const bf16* Qg = Q + (size_t)bh * (N_L * N_HD);
  const bf16* Kg = K + (size_t)bh * (N_L * N_HD);
  const bf16* Vg = Vt + (size_t)bh * (N_L * N_HD);

#pragma unroll
  for (int t = 0; t < 8; ++t) {
    int idx = tid + 512 * t;            // 16B-granule index, 4096 total
    int row = idx >> 4, g = idx & 15;
    const bf16* src = Kg + row * N_HD + ((g ^ (row & 7)) << 3);
    __builtin_amdgcn_global_load_lds(
        (const __attribute__((address_space(1))) void*)src,
        (__attribute__((address_space(3))) void*)(Kl + (size_t)wave * 512 + (size_t)t * 4096),
        16, 0, 0);
  }
  __syncthreads();

  const float scale = 0.08838834764831843f;  // 1/sqrt(128)

  for (int half = 0; half < 2; ++half) {
    const int qb = half ? (15 - wave) : wave;
    const int q0 = qb * 16;

    bf16x8 qf[4];
#pragma unroll
    for (int dk = 0; dk < 4; ++dk)
      qf[dk] = *(const bf16x8*)(Qg + (size_t)(q0 + c) * N_HD + dk * 32 + g8 * 8);

    f32x4 o[8];
#pragma unroll
    for (int dj = 0; dj < 8; ++dj) o[dj] = (f32x4){0.f, 0.f, 0.f, 0.f};
    f32x4 mrow = (f32x4){-INFINITY, -INFINITY, -INFINITY, -INFINITY};
    f32x4 lrow = (f32x4){0.f, 0.f, 0.f, 0.f};

    const int nsteps = ((q0 + 15) >> 5) + 1;
    for (int js = 0; js < nsteps; ++js) {
      const int j0 = js * 32;

      bf16x8 vf[4];
#pragma unroll
      for (int dj = 0; dj < 4; ++dj)
        vf[dj] = *(const bf16x8*)(Vg + (size_t)(dj * 16 + c) * N_L + j0 + g8 * 8);

      f32x4 s0 = (f32x4){0.f, 0.f, 0.f, 0.f};
      f32x4 s1 = (f32x4){0.f, 0.f, 0.f, 0.f};
#pragma unroll
      for (int dk = 0; dk < 4; ++dk) {
        int row0 = j0 + c;
        int row1 = j0 + 16 + c;
        bf16x8 kf0 = *(const bf16x8*)(Kl + row0 * N_HD + (((dk * 4 + g8) ^ (row0 & 7)) << 3));
        bf16x8 kf1 = *(const bf16x8*)(Kl + row1 * N_HD + (((dk * 4 + g8) ^ (row1 & 7)) << 3));
        s0 = __builtin_amdgcn_mfma_f32_16x16x32_bf16(qf[dk], kf0, s0, 0, 0, 0);
        s1 = __builtin_amdgcn_mfma_f32_16x16x32_bf16(qf[dk], kf1, s1, 0, 0, 0);
      }

      // mask whenever the tile touches the upper triangle: j0+31 > q0
      f32x4 sv0, sv1;
#pragma unroll
      for (int r = 0; r < 4; ++r) { sv0[r] = s0[r] * scale; sv1[r] = s1[r] * scale; }
      if (j0 + 31 > q0) {
#pragma unroll
        for (int r = 0; r < 4; ++r) {
          int q = q0 + g8 * 4 + r;
          if (j0 + c > q)      sv0[r] = -INFINITY;
          if (j0 + 16 + c > q) sv1[r] = -INFINITY;
        }
      }

      f32x4 mx = max4(sv0, sv1);
      mx = max4(mx, shflx4(mx, 1));
      mx = max4(mx, shflx4(mx, 2));
      mx = max4(mx, shflx4(mx, 4));
      mx = max4(mx, shflx4(mx, 8));
      f32x4 mnew = max4(mrow, mx);
      f32x4 resc, p0, p1;
#pragma unroll
      for (int r = 0; r < 4; ++r) {
        resc[r] = __expf(mrow[r] - mnew[r]);
        p0[r] = __expf(sv0[r] - mnew[r]);
        p1[r] = __expf(sv1[r] - mnew[r]);
      }
      f32x4 rsum = p0 + p1;
      rsum += shflx4(rsum, 1);
      rsum += shflx4(rsum, 2);
      rsum += shflx4(rsum, 4);
      rsum += shflx4(rsum, 8);
      lrow = lrow * resc + rsum;
      mrow = mnew;
#pragma unroll
      for (int dj = 0; dj < 8; ++dj) o[dj] *= resc;

#pragma unroll
      for (int r = 0; r < 4; ++r) {
        Pl[wave][g8 * 4 + r][c] = (bf16)p0[r];
        Pl[wave][g8 * 4 + r][16 + c] = (bf16)p1[r];
      }
      bf16x8 pf = *(const bf16x8*)&Pl[wave][c][g8 * 8];

      bf16x8 vg[4];
#pragma unroll
      for (int dj = 0; dj < 4; ++dj)
        vg[dj] = *(const bf16x8*)(Vg + (size_t)((dj + 4) * 16 + c) * N_L + j0 + g8 * 8);

#pragma unroll
      for (int dj = 0; dj < 4; ++dj)
        o[dj] = __builtin_amdgcn_mfma_f32_16x16x32_bf16(pf, vf[dj], o[dj], 0, 0, 0);
#pragma unroll
      for (int dj = 0; dj < 4; ++dj)
        o[dj + 4] = __builtin_amdgcn_mfma_f32_16x16x32_bf16(pf, vg[dj], o[dj + 4], 0, 0, 0);
    }

    f32x4 inv;
#pragma unroll
    for (int r = 0; r < 4; ++r) inv[r] = 1.0f / lrow[r];
#pragma unroll
    for (int dj = 0; dj < 8; ++dj) {
      f32x4 ov = o[dj] * inv;
#pragma unroll
      for (int r = 0; r < 4; ++r) {
        int q = q0 + g8 * 4 + r;
        int d = dj * 16 + c;
        O[(((size_t)b * N_L + q) * N_H + h) * N_HD + d] = (bf16)ov[r];
      }
    }
  }
}

// ---------------- launch ----------------
extern "C" void kernel_launch(void* const* d_in, const int* in_sizes, int n_in,
                              void* d_out, int out_size, void* d_ws, size_t ws_size,
                              hipStream_t stream) {
  const float* x  = (const float*)d_in[0];
  const float* wq = (const float*)d_in[1];
  const float* bq = (const float*)d_in[2];
  const float* wk = (const float*)d_in[3];
  const float* bk = (const float*)d_in[4];
  const float* wv = (const float*)d_in[5];
  const float* bv = (const float*)d_in[6];
  const float* wo = (const float*)d_in[7];
  const float* bo = (const float*)d_in[8];

  char* ws = (char*)d_ws;
  const size_t WSZ = (size_t)N_D * N_D * sizeof(bf16);    // 8 MB per transposed weight
  const size_t XSZ = (size_t)M_TOT * N_D * sizeof(bf16);  // 64 MB per activation tensor
  bf16* wqT = (bf16*)(ws);
  bf16* wkT = (bf16*)(ws + WSZ);
  bf16* wvT = (bf16*)(ws + 2 * WSZ);
  bf16* woT = (bf16*)(ws + 3 * WSZ);
  bf16* xb  = (bf16*)(ws + 4 * WSZ);
  bf16* Qb  = (bf16*)(ws + 4 * WSZ + XSZ);
  bf16* Kb  = (bf16*)(ws + 4 * WSZ + 2 * XSZ);
  bf16* Vb  = (bf16*)(ws + 4 * WSZ + 3 * XSZ);  // holds V^T: [b][h][d][l]
  bf16* Ob  = (bf16*)(ws + 4 * WSZ + 4 * XSZ);
  float2* tab = (float2*)(ws + 4 * WSZ + 5 * XSZ);

  k_cast_x<<<2048, 256, 0, stream>>>(x, xb, M_TOT * N_D / 4);
  dim3 tb(32, 32), tg(64, 64);
  k_transpose_w<<<tg, tb, 0, stream>>>(wq, wqT);
  k_transpose_w<<<tg, tb, 0, stream>>>(wk, wkT);
  k_transpose_w<<<tg, tb, 0, stream>>>(wv, wvT);
  k_transpose_w<<<tg, tb, 0, stream>>>(wo, woT);
  k_trig<<<64, 256, 0, stream>>>(tab);

  const int grid = (M_TOT / 256) * (N_D / 128);  // 1024
  k_gemm256<3><<<grid, 256, 0, stream>>>(xb, wqT, bq, Qb, tab);   // Q proj + RoPE
  k_gemm256<3><<<grid, 256, 0, stream>>>(xb, wkT, bk, Kb, tab);   // K proj + RoPE
  k_gemm256<2><<<grid, 256, 0, stream>>>(xb, wvT, bv, Vb, tab);   // V proj, transposed

  k_attn_mfma<<<1024, 512, 0, stream>>>(Qb, Kb, Vb, Ob);
  k_gemm256<1><<<grid, 256, 0, stream>>>(Ob, woT, bo, d_out, tab);
}